// Round 1
// baseline (2177.627 us; speedup 1.0000x reference)
//
#include <hip/hip_runtime.h>
#include <hip/hip_bf16.h>

// BitNet-style ternary MLP: out = relu(x @ Wfc_q^T * s_fc)^2 @ Wproj_q^T * s_proj
// B=8 S=4096 D=2048 H=5120 -> M=32768.
// GEMMs in bf16 MFMA with EXACT ternary q (scale factored out, applied fp32).

typedef __attribute__((ext_vector_type(8))) short short8;
typedef __attribute__((ext_vector_type(4))) float f32x4;

#define BM 128
#define BN 128
#define BK 64

__device__ __forceinline__ unsigned short f2bf(float f) {
  unsigned int u = __float_as_uint(f);
  u += 0x7FFFu + ((u >> 16) & 1u);   // RNE
  return (unsigned short)(u >> 16);
}

__device__ __forceinline__ void gload_lds16(const void* gsrc, void* ldst) {
  __builtin_amdgcn_global_load_lds(
      (const __attribute__((address_space(1))) unsigned int*)gsrc,
      (__attribute__((address_space(3))) unsigned int*)ldst, 16, 0, 0);
}

// ---------- pass 1: |w| sum partials (deterministic, fp64 accumulate) ----------
__global__ void k_reduce_abs(const float4* __restrict__ w, int n4,
                             double* __restrict__ partial) {
  __shared__ double sm[256];
  double s = 0.0;
  const int stride = gridDim.x * blockDim.x;
  for (int i = blockIdx.x * blockDim.x + threadIdx.x; i < n4; i += stride) {
    float4 v = w[i];
    s += (double)fabsf(v.x);
    s += (double)fabsf(v.y);
    s += (double)fabsf(v.z);
    s += (double)fabsf(v.w);
  }
  sm[threadIdx.x] = s;
  __syncthreads();
  for (int off = 128; off > 0; off >>= 1) {
    if (threadIdx.x < off) sm[threadIdx.x] += sm[threadIdx.x + off];
    __syncthreads();
  }
  if (threadIdx.x == 0) partial[blockIdx.x] = sm[0];
}

// ---------- pass 2: finalize abs_mean / thr for both weights ----------
__global__ void k_finalize(const double* __restrict__ partial,
                           float* __restrict__ scales, double inv_n) {
  __shared__ double sm[256];
  const int t = threadIdx.x;
  for (int seg = 0; seg < 2; ++seg) {
    const double* p = partial + seg * 1024;
    double s = p[t * 4] + p[t * 4 + 1] + p[t * 4 + 2] + p[t * 4 + 3];
    sm[t] = s;
    __syncthreads();
    for (int off = 128; off > 0; off >>= 1) {
      if (t < off) sm[t] += sm[t + off];
      __syncthreads();
    }
    if (t == 0) {
      float am = (float)(sm[0] * inv_n);
      am = fmaxf(am, 1e-5f);
      scales[seg * 2] = am;          // abs_mean
      scales[seg * 2 + 1] = 0.7f * am;  // threshold
    }
    __syncthreads();
  }
}

// ---------- ternarize: fp32 w -> bf16 q in {-1,0,+1} ----------
__global__ void k_ternarize(const float4* __restrict__ w, ushort4* __restrict__ q,
                            const float* __restrict__ scales, int sidx, int n4) {
  const float thr = scales[sidx * 2 + 1];
  const int stride = gridDim.x * blockDim.x;
  for (int i = blockIdx.x * blockDim.x + threadIdx.x; i < n4; i += stride) {
    float4 v = w[i];
    ushort4 o;
    o.x = v.x > thr ? 0x3F80u : (v.x < -thr ? 0xBF80u : 0u);
    o.y = v.y > thr ? 0x3F80u : (v.y < -thr ? 0xBF80u : 0u);
    o.z = v.z > thr ? 0x3F80u : (v.z < -thr ? 0xBF80u : 0u);
    o.w = v.w > thr ? 0x3F80u : (v.w < -thr ? 0xBF80u : 0u);
    q[i] = o;
  }
}

// ---------- x: fp32 -> bf16 ----------
__global__ void k_f32_to_bf16(const float4* __restrict__ x, ushort4* __restrict__ o,
                              int n4) {
  const int stride = gridDim.x * blockDim.x;
  for (int i = blockIdx.x * blockDim.x + threadIdx.x; i < n4; i += stride) {
    float4 v = x[i];
    ushort4 r;
    r.x = f2bf(v.x);
    r.y = f2bf(v.y);
    r.z = f2bf(v.z);
    r.w = f2bf(v.w);
    o[i] = r;
  }
}

// ---------- GEMM C = A * B^T  (A[M][K], B[N][K], bf16 -> fp32 acc) ----------
// EPI 0: h = (relu(acc)*s)^2 = relu(acc)^2 * s^2 -> bf16
// EPI 1: out = acc * s -> fp32
template <int EPI>
__global__ __launch_bounds__(256) void k_gemm_bt(
    const unsigned short* __restrict__ A, const unsigned short* __restrict__ B,
    void* __restrict__ Cout, int M, int N, int K,
    const float* __restrict__ scales, int sidx) {
  __shared__ __align__(16) unsigned short lA[BM * BK];
  __shared__ __align__(16) unsigned short lB[BN * BK];

  const int tid = threadIdx.x;
  const int lane = tid & 63;
  const int wv = tid >> 6;   // wave 0..3
  const int wr = wv >> 1;    // wave row (0..1) -> 64 rows each
  const int wc = wv & 1;     // wave col

  const int bn = blockIdx.x;
  const int bm = blockIdx.y;
  const int rowA0 = bm * BM;
  const int rowB0 = bn * BN;

  // staging geometry: instruction i covers LDS chunk (i*4+wv)*1024 bytes;
  // lane writes 16B at chunk*1024 + lane*16 (HW: wave-uniform base + lane*size)
  const int sub = lane >> 3;        // row within 8-row chunk
  const int col8 = (lane & 7) * 8;  // bf16 col start

  f32x4 zero = {0.f, 0.f, 0.f, 0.f};
  f32x4 acc[4][4];
#pragma unroll
  for (int i = 0; i < 4; ++i)
#pragma unroll
    for (int j = 0; j < 4; ++j) acc[i][j] = zero;

  const int nk = K / BK;
  for (int kt = 0; kt < nk; ++kt) {
    const int k0 = kt * BK;
    __syncthreads();  // prior tile's reads done before overwrite
#pragma unroll
    for (int i = 0; i < 4; ++i) {
      const int chunk = i * 4 + wv;       // 0..15
      const int r = chunk * 8 + sub;      // 0..127
      gload_lds16(A + (size_t)(rowA0 + r) * K + (k0 + col8), &lA[chunk * 512]);
      gload_lds16(B + (size_t)(rowB0 + r) * K + (k0 + col8), &lB[chunk * 512]);
    }
    __syncthreads();  // compiler drains vmcnt(0) before barrier -> tiles ready
#pragma unroll
    for (int ks = 0; ks < 2; ++ks) {
      const int kb = ks * 32 + (lane >> 4) * 8;  // k offset within tile
      const int fr = lane & 15;
      short8 af[4], bfr[4];
#pragma unroll
      for (int i = 0; i < 4; ++i)
        af[i] = *(const short8*)&lA[(wr * 64 + i * 16 + fr) * BK + kb];
#pragma unroll
      for (int j = 0; j < 4; ++j)
        bfr[j] = *(const short8*)&lB[(wc * 64 + j * 16 + fr) * BK + kb];
#pragma unroll
      for (int i = 0; i < 4; ++i)
#pragma unroll
        for (int j = 0; j < 4; ++j)
          acc[i][j] = __builtin_amdgcn_mfma_f32_16x16x32_bf16(af[i], bfr[j],
                                                              acc[i][j], 0, 0, 0);
    }
  }

  // epilogue: C/D layout col = lane&15, row = (lane>>4)*4 + q
  const float s = scales[sidx * 2];
  const int ccol = rowB0 + wc * 64 + (lane & 15);
  const int crow = rowA0 + wr * 64 + (lane >> 4) * 4;
  if (EPI == 0) {
    const float s2 = s * s;
    unsigned short* C = (unsigned short*)Cout;
#pragma unroll
    for (int i = 0; i < 4; ++i)
#pragma unroll
      for (int j = 0; j < 4; ++j)
#pragma unroll
        for (int q = 0; q < 4; ++q) {
          float v = acc[i][j][q];
          v = fmaxf(v, 0.0f);
          v = v * v * s2;
          C[(size_t)(crow + i * 16 + q) * N + (ccol + j * 16)] = f2bf(v);
        }
  } else {
    float* C = (float*)Cout;
#pragma unroll
    for (int i = 0; i < 4; ++i)
#pragma unroll
      for (int j = 0; j < 4; ++j)
#pragma unroll
        for (int q = 0; q < 4; ++q)
          C[(size_t)(crow + i * 16 + q) * N + (ccol + j * 16)] =
              acc[i][j][q] * s;
  }
}

extern "C" void kernel_launch(void* const* d_in, const int* in_sizes, int n_in,
                              void* d_out, int out_size, void* d_ws, size_t ws_size,
                              hipStream_t stream) {
  const int Mdim = 32768;  // B*S
  const int Ddim = 2048;
  const int Hdim = 5120;
  const int NW = Hdim * Ddim;  // 10485760 elements per weight

  const float* x = (const float*)d_in[0];
  const float* w_fc = (const float*)d_in[1];
  const float* w_proj = (const float*)d_in[2];
  float* out = (float*)d_out;

  char* ws = (char*)d_ws;
  double* partial = (double*)ws;                       // 2048 doubles = 16 KB
  float* scales = (float*)(ws + 16384);                // 4 floats
  unsigned short* wq_fc = (unsigned short*)(ws + 32768);          // 20 MB
  unsigned short* wq_proj = wq_fc + (size_t)NW;                   // 20 MB
  unsigned short* xbf = wq_proj + (size_t)NW;                     // 128 MB
  unsigned short* hbf = xbf + (size_t)Mdim * Ddim;                // 320 MB
  // total ws use ~488 MB

  // 1) abs-mean reductions (deterministic, fp64)
  k_reduce_abs<<<1024, 256, 0, stream>>>((const float4*)w_fc, NW / 4, partial);
  k_reduce_abs<<<1024, 256, 0, stream>>>((const float4*)w_proj, NW / 4,
                                         partial + 1024);
  k_finalize<<<1, 256, 0, stream>>>(partial, scales, 1.0 / (double)NW);

  // 2) ternarize weights -> bf16 q
  k_ternarize<<<2048, 256, 0, stream>>>((const float4*)w_fc, (ushort4*)wq_fc,
                                        scales, 0, NW / 4);
  k_ternarize<<<2048, 256, 0, stream>>>((const float4*)w_proj, (ushort4*)wq_proj,
                                        scales, 1, NW / 4);

  // 3) x -> bf16
  k_f32_to_bf16<<<2048, 256, 0, stream>>>((const float4*)x, (ushort4*)xbf,
                                          (Mdim * Ddim) / 4);

  // 4) h = relu(x @ Wfc^T * s)^2  [M x H] bf16
  k_gemm_bt<0><<<dim3(Hdim / BN, Mdim / BM), 256, 0, stream>>>(
      xbf, wq_fc, hbf, Mdim, Hdim, Ddim, scales, 0);

  // 5) out = h @ Wproj^T * s  [M x D] fp32
  k_gemm_bt<1><<<dim3(Ddim / BN, Mdim / BM), 256, 0, stream>>>(
      hbf, wq_proj, out, Mdim, Ddim, Hdim, scales, 1);
}

// Round 2
// 1271.315 us; speedup vs baseline: 1.7129x; 1.7129x over previous
//
#include <hip/hip_runtime.h>
#include <hip/hip_bf16.h>

// BitNet-style ternary MLP: out = relu(x @ Wfc_q^T * s_fc)^2 @ Wproj_q^T * s_proj
// B=8 S=4096 D=2048 H=5120 -> M=32768.
// GEMMs: 256x256 tile, BK=64, 8 waves, 4-phase/K-tile pipeline with counted
// vmcnt(6) (T3+T4), LDS XOR-swizzle via pre-swizzled global src (T2, rule 21),
// setprio around MFMA (T5), bijective XCD blockIdx swizzle (T1).

typedef __attribute__((ext_vector_type(8))) short short8;
typedef __attribute__((ext_vector_type(4))) float f32x4;

#define BM 256
#define BN 256
#define BK 64

__device__ __forceinline__ unsigned short f2bf(float f) {
  unsigned int u = __float_as_uint(f);
  u += 0x7FFFu + ((u >> 16) & 1u);  // RNE
  return (unsigned short)(u >> 16);
}

__device__ __forceinline__ void gload_lds16(const void* gsrc, void* ldst) {
  __builtin_amdgcn_global_load_lds(
      (const __attribute__((address_space(1))) unsigned int*)gsrc,
      (__attribute__((address_space(3))) unsigned int*)ldst, 16, 0, 0);
}

// ---------- pass 1: |w| sum partials (deterministic, fp64 accumulate) ----------
__global__ void k_reduce_abs(const float4* __restrict__ w, int n4,
                             double* __restrict__ partial) {
  __shared__ double sm[256];
  double s = 0.0;
  const int stride = gridDim.x * blockDim.x;
  for (int i = blockIdx.x * blockDim.x + threadIdx.x; i < n4; i += stride) {
    float4 v = w[i];
    s += (double)fabsf(v.x);
    s += (double)fabsf(v.y);
    s += (double)fabsf(v.z);
    s += (double)fabsf(v.w);
  }
  sm[threadIdx.x] = s;
  __syncthreads();
  for (int off = 128; off > 0; off >>= 1) {
    if (threadIdx.x < off) sm[threadIdx.x] += sm[threadIdx.x + off];
    __syncthreads();
  }
  if (threadIdx.x == 0) partial[blockIdx.x] = sm[0];
}

// ---------- pass 2: finalize abs_mean / thr for both weights ----------
__global__ void k_finalize(const double* __restrict__ partial,
                           float* __restrict__ scales, double inv_n) {
  __shared__ double sm[256];
  const int t = threadIdx.x;
  for (int seg = 0; seg < 2; ++seg) {
    const double* p = partial + seg * 1024;
    double s = p[t * 4] + p[t * 4 + 1] + p[t * 4 + 2] + p[t * 4 + 3];
    sm[t] = s;
    __syncthreads();
    for (int off = 128; off > 0; off >>= 1) {
      if (t < off) sm[t] += sm[t + off];
      __syncthreads();
    }
    if (t == 0) {
      float am = (float)(sm[0] * inv_n);
      am = fmaxf(am, 1e-5f);
      scales[seg * 2] = am;             // abs_mean
      scales[seg * 2 + 1] = 0.7f * am;  // threshold
    }
    __syncthreads();
  }
}

// ---------- ternarize: fp32 w -> bf16 q in {-1,0,+1} ----------
__global__ void k_ternarize(const float4* __restrict__ w, ushort4* __restrict__ q,
                            const float* __restrict__ scales, int sidx, int n4) {
  const float thr = scales[sidx * 2 + 1];
  const int stride = gridDim.x * blockDim.x;
  for (int i = blockIdx.x * blockDim.x + threadIdx.x; i < n4; i += stride) {
    float4 v = w[i];
    ushort4 o;
    o.x = v.x > thr ? 0x3F80u : (v.x < -thr ? 0xBF80u : 0u);
    o.y = v.y > thr ? 0x3F80u : (v.y < -thr ? 0xBF80u : 0u);
    o.z = v.z > thr ? 0x3F80u : (v.z < -thr ? 0xBF80u : 0u);
    o.w = v.w > thr ? 0x3F80u : (v.w < -thr ? 0xBF80u : 0u);
    q[i] = o;
  }
}

// ---------- x: fp32 -> bf16 ----------
__global__ void k_f32_to_bf16(const float4* __restrict__ x, ushort4* __restrict__ o,
                              int n4) {
  const int stride = gridDim.x * blockDim.x;
  for (int i = blockIdx.x * blockDim.x + threadIdx.x; i < n4; i += stride) {
    float4 v = x[i];
    ushort4 r;
    r.x = f2bf(v.x);
    r.y = f2bf(v.y);
    r.z = f2bf(v.z);
    r.w = f2bf(v.w);
    o[i] = r;
  }
}

// ================= 256x256 8-wave 4-phase pipelined GEMM =================
// C = A * B^T. A[M][K], B[N][K] bf16; fp32 acc.
// LDS per buffer: A[256][64], B[256][64]; double-buffered = 128 KiB.
// Swizzle: LDS linear; global src col pre-permuted so that
// LDS[row][c] = G[row][c ^ 8*(row&7)] (elems); reads XOR the same.

// one global_load_lds: wave-uniform LDS base (elems), 8 rows of 64 bf16
#define ST1(Gst, base, r0, k0)                          \
  gload_lds16(Gst + (size_t)(r0) * K + (k0),            \
              (void*)(lptr + (base) + (r0) * 64))

#define ST_AQ0(pp, k0) do { ST1(Ast, (pp)*32768, w8, k0);        ST1(Ast, (pp)*32768, 128 + w8, k0); } while (0)
#define ST_AQ1(pp, k0) do { ST1(Ast, (pp)*32768, 64 + w8, k0);   ST1(Ast, (pp)*32768, 192 + w8, k0); } while (0)
#define ST_BQ0(pp, k0) do { ST1(Bst, (pp)*32768 + 16384, rb, k0);      ST1(Bst, (pp)*32768 + 16384, 128 + rb, k0); } while (0)
#define ST_BQ1(pp, k0) do { ST1(Bst, (pp)*32768 + 16384, 32 + rb, k0); ST1(Bst, (pp)*32768 + 16384, 160 + rb, k0); } while (0)

#define LDA(p_, qr)                                                            \
  do {                                                                         \
    const unsigned short* ab =                                                 \
        lptr + (p_) * 32768 + (wr * 128 + (qr) * 64 + fr) * 64;                \
    _Pragma("unroll") for (int ri = 0; ri < 4; ++ri) {                         \
      af[ri][0] = *(const short8*)(ab + ri * 1024 + csw0);                     \
      af[ri][1] = *(const short8*)(ab + ri * 1024 + csw1);                     \
    }                                                                          \
  } while (0)

#define LDB(p_, qc)                                                            \
  do {                                                                         \
    const unsigned short* bb =                                                 \
        lptr + (p_) * 32768 + 16384 + (wc * 64 + (qc) * 32 + fr) * 64;         \
    _Pragma("unroll") for (int ci = 0; ci < 2; ++ci) {                         \
      bq[ci][0] = *(const short8*)(bb + ci * 1024 + csw0);                     \
      bq[ci][1] = *(const short8*)(bb + ci * 1024 + csw1);                     \
    }                                                                          \
  } while (0)

#define MFMA_PHASE(qr, qc)                                                     \
  do {                                                                         \
    __builtin_amdgcn_s_setprio(1);                                             \
    _Pragma("unroll") for (int kk = 0; kk < 2; ++kk)                           \
    _Pragma("unroll") for (int ri = 0; ri < 4; ++ri)                           \
    _Pragma("unroll") for (int ci = 0; ci < 2; ++ci)                           \
      acc[(qr) * 4 + ri][(qc) * 2 + ci] =                                      \
          __builtin_amdgcn_mfma_f32_16x16x32_bf16(                             \
              af[ri][kk], bq[ci][kk], acc[(qr) * 4 + ri][(qc) * 2 + ci], 0, 0, \
              0);                                                              \
    __builtin_amdgcn_s_setprio(0);                                             \
  } while (0)

#define BAR()                           \
  do {                                  \
    asm volatile("" ::: "memory");      \
    __builtin_amdgcn_s_barrier();       \
    asm volatile("" ::: "memory");      \
  } while (0)

template <int EPI>
__global__ __launch_bounds__(512, 2) void k_gemm_bt(
    const unsigned short* __restrict__ A, const unsigned short* __restrict__ B,
    void* __restrict__ Cout, int M, int N, int K,
    const float* __restrict__ scales, int sidx, int nbx) {
  __shared__ __align__(16) unsigned short lds[2 * 2 * 256 * 64];  // 128 KiB
  unsigned short* lptr = lds;

  const int tid = threadIdx.x;
  const int lane = tid & 63;
  const int w = tid >> 6;   // wave 0..7
  const int wr = w >> 2;    // 0..1 -> 128 rows
  const int wc = w & 3;     // 0..3 -> 64 cols

  // T1: bijective XCD swizzle (gridDim.x % 8 == 0)
  const int nwg = gridDim.x;
  const int cpx = nwg >> 3;
  const int bid = blockIdx.x;
  const int swz = (bid & 7) * cpx + (bid >> 3);
  const int bm = swz / nbx;
  const int bn = swz % nbx;
  const int rowA0 = bm * BM;
  const int rowB0 = bn * BN;

  // staging lane geometry: row within 8-row chunk + pre-swizzled source col
  const int srow = lane >> 3;
  const int scol = ((lane & 7) ^ srow) << 3;  // bf16 elems
  const unsigned short* Ast = A + (size_t)(rowA0 + srow) * K + scol;
  const unsigned short* Bst = B + (size_t)(rowB0 + srow) * K + scol;

  // frag-read lane geometry (read col XORed with 8*(row&7), row&7 == fr&7)
  const int fr = lane & 15;
  const int kgrp = lane >> 4;
  const int csw0 = (kgrp << 3) ^ ((fr & 7) << 3);
  const int csw1 = (32 + (kgrp << 3)) ^ ((fr & 7) << 3);

  const int w8 = w << 3;
  const int rb = ((w >> 2) << 6) + ((w & 3) << 3);

  f32x4 acc[8][4];
#pragma unroll
  for (int i = 0; i < 8; ++i)
#pragma unroll
    for (int j = 0; j < 4; ++j) acc[i][j] = (f32x4){0.f, 0.f, 0.f, 0.f};

  short8 af[4][2], bq[2][2];

  const int nk = K / BK;

  // prologue (FIFO): tile0 {Bq0,Aq1,Aq0,Bq1}, tile1 {Bq0,Aq1}
  ST_BQ0(0, 0);
  ST_AQ1(0, 0);
  ST_AQ0(0, 0);
  ST_BQ1(0, 0);
  if (nk > 1) {
    ST_BQ0(1, BK);
    ST_AQ1(1, BK);
  }

  int p = 0;
  for (int T = 0; T < nk; ++T, p ^= 1) {
    const int pn = p ^ 1;
    const int k1 = (T + 1) * BK;
    const int k2 = (T + 2) * BK;

    // ---- P1 (qr=0, qc=0): single counted wait per K-tile ----
    if (T + 1 < nk) {
      ST_AQ0(pn, k1);
      asm volatile("s_waitcnt vmcnt(6)" ::: "memory");
    } else {
      asm volatile("s_waitcnt vmcnt(0)" ::: "memory");
    }
    __builtin_amdgcn_s_barrier();
    asm volatile("" ::: "memory");
    LDA(p, 0);
    LDB(p, 0);
    MFMA_PHASE(0, 0);
    BAR();

    // ---- P2 (qr=1, qc=0): reuse bq ----
    if (T + 1 < nk) ST_BQ1(pn, k1);
    LDA(p, 1);
    MFMA_PHASE(1, 0);
    BAR();

    // ---- P3 (qr=1, qc=1): reuse af ----
    if (T + 2 < nk) ST_BQ0(p, k2);
    LDB(p, 1);
    MFMA_PHASE(1, 1);
    BAR();

    // ---- P4 (qr=0, qc=1): reuse bq, re-read A qr0 ----
    if (T + 2 < nk) ST_AQ1(p, k2);
    LDA(p, 0);
    MFMA_PHASE(0, 1);
    BAR();
  }

  // epilogue: C/D layout col = lane&15, row = (lane>>4)*4 + q
  const float s = scales[sidx * 2];
  const int crow0 = rowA0 + wr * 128 + (lane >> 4) * 4;
  const int ccol0 = rowB0 + wc * 64 + (lane & 15);
  if (EPI == 0) {
    const float s2 = s * s;
    unsigned short* C = (unsigned short*)Cout;
#pragma unroll
    for (int ri = 0; ri < 8; ++ri)
#pragma unroll
      for (int ci = 0; ci < 4; ++ci)
#pragma unroll
        for (int q = 0; q < 4; ++q) {
          float v = acc[ri][ci][q];
          v = fmaxf(v, 0.0f);
          v = v * v * s2;
          C[(size_t)(crow0 + ri * 16 + q) * N + (ccol0 + ci * 16)] = f2bf(v);
        }
  } else {
    float* C = (float*)Cout;
#pragma unroll
    for (int ri = 0; ri < 8; ++ri)
#pragma unroll
      for (int ci = 0; ci < 4; ++ci)
#pragma unroll
        for (int q = 0; q < 4; ++q)
          C[(size_t)(crow0 + ri * 16 + q) * N + (ccol0 + ci * 16)] =
              acc[ri][ci][q] * s;
  }
}

extern "C" void kernel_launch(void* const* d_in, const int* in_sizes, int n_in,
                              void* d_out, int out_size, void* d_ws, size_t ws_size,
                              hipStream_t stream) {
  const int Mdim = 32768;  // B*S
  const int Ddim = 2048;
  const int Hdim = 5120;
  const int NW = Hdim * Ddim;  // elements per weight

  const float* x = (const float*)d_in[0];
  const float* w_fc = (const float*)d_in[1];
  const float* w_proj = (const float*)d_in[2];
  float* out = (float*)d_out;

  char* ws = (char*)d_ws;
  double* partial = (double*)ws;                          // 16 KB
  float* scales = (float*)(ws + 16384);                   // 4 floats
  unsigned short* wq_fc = (unsigned short*)(ws + 32768);  // 20 MB
  unsigned short* wq_proj = wq_fc + (size_t)NW;           // 20 MB
  unsigned short* xbf = wq_proj + (size_t)NW;             // 128 MB
  unsigned short* hbf = xbf + (size_t)Mdim * Ddim;        // 320 MB

  // 1) abs-mean reductions (deterministic, fp64)
  k_reduce_abs<<<1024, 256, 0, stream>>>((const float4*)w_fc, NW / 4, partial);
  k_reduce_abs<<<1024, 256, 0, stream>>>((const float4*)w_proj, NW / 4,
                                         partial + 1024);
  k_finalize<<<1, 256, 0, stream>>>(partial, scales, 1.0 / (double)NW);

  // 2) ternarize weights -> bf16 q
  k_ternarize<<<2048, 256, 0, stream>>>((const float4*)w_fc, (ushort4*)wq_fc,
                                        scales, 0, NW / 4);
  k_ternarize<<<2048, 256, 0, stream>>>((const float4*)w_proj, (ushort4*)wq_proj,
                                        scales, 1, NW / 4);

  // 3) x -> bf16
  k_f32_to_bf16<<<2048, 256, 0, stream>>>((const float4*)x, (ushort4*)xbf,
                                          (Mdim * Ddim) / 4);

  // 4) h = relu(x @ Wfc^T * s)^2  [M x H] bf16
  k_gemm_bt<0><<<dim3((Hdim / BN) * (Mdim / BM)), 512, 0, stream>>>(
      xbf, wq_fc, hbf, Mdim, Hdim, Ddim, scales, 0, Hdim / BN);

  // 5) out = h @ Wproj^T * s  [M x D] fp32
  k_gemm_bt<1><<<dim3((Ddim / BN) * (Mdim / BM)), 512, 0, stream>>>(
      hbf, wq_proj, out, Mdim, Ddim, Hdim, scales, 1, Ddim / BN);
}

// Round 3
// 1246.998 us; speedup vs baseline: 1.7463x; 1.0195x over previous
//
#include <hip/hip_runtime.h>
#include <hip/hip_bf16.h>

// BitNet-style ternary MLP: out = relu(x @ Wfc_q^T * s_fc)^2 @ Wproj_q^T * s_proj
// B=8 S=4096 D=2048 H=5120 -> M=32768.
// GEMMs: 256x256 tile, BK=64, 8 waves, 4-phase/K-tile schedule per the m201
// template: ds_reads hoisted PRE-barrier, lgkmcnt(0) post-barrier, single
// counted vmcnt(4) at tile boundary (T3+T4), A-frags held in regs across the
// tile (24 ds_read_b128/tile), LDS XOR-swizzle via pre-swizzled global src
// (T2), setprio around MFMA (T5), bijective XCD swizzle (T1).

typedef __attribute__((ext_vector_type(8))) short short8;
typedef __attribute__((ext_vector_type(4))) float f32x4;

#define BM 256
#define BN 256
#define BK 64

__device__ __forceinline__ unsigned short f2bf(float f) {
  unsigned int u = __float_as_uint(f);
  u += 0x7FFFu + ((u >> 16) & 1u);  // RNE
  return (unsigned short)(u >> 16);
}

__device__ __forceinline__ void gload_lds16(const void* gsrc, void* ldst) {
  __builtin_amdgcn_global_load_lds(
      (const __attribute__((address_space(1))) unsigned int*)gsrc,
      (__attribute__((address_space(3))) unsigned int*)ldst, 16, 0, 0);
}

// ---------- pass 1: |w| sum partials (deterministic, fp64 accumulate) ----------
__global__ void k_reduce_abs(const float4* __restrict__ w, int n4,
                             double* __restrict__ partial) {
  __shared__ double sm[256];
  double s = 0.0;
  const int stride = gridDim.x * blockDim.x;
  for (int i = blockIdx.x * blockDim.x + threadIdx.x; i < n4; i += stride) {
    float4 v = w[i];
    s += (double)fabsf(v.x);
    s += (double)fabsf(v.y);
    s += (double)fabsf(v.z);
    s += (double)fabsf(v.w);
  }
  sm[threadIdx.x] = s;
  __syncthreads();
  for (int off = 128; off > 0; off >>= 1) {
    if (threadIdx.x < off) sm[threadIdx.x] += sm[threadIdx.x + off];
    __syncthreads();
  }
  if (threadIdx.x == 0) partial[blockIdx.x] = sm[0];
}

// ---------- pass 2: finalize abs_mean / thr for both weights ----------
__global__ void k_finalize(const double* __restrict__ partial,
                           float* __restrict__ scales, double inv_n) {
  __shared__ double sm[256];
  const int t = threadIdx.x;
  for (int seg = 0; seg < 2; ++seg) {
    const double* p = partial + seg * 1024;
    double s = p[t * 4] + p[t * 4 + 1] + p[t * 4 + 2] + p[t * 4 + 3];
    sm[t] = s;
    __syncthreads();
    for (int off = 128; off > 0; off >>= 1) {
      if (t < off) sm[t] += sm[t + off];
      __syncthreads();
    }
    if (t == 0) {
      float am = (float)(sm[0] * inv_n);
      am = fmaxf(am, 1e-5f);
      scales[seg * 2] = am;             // abs_mean
      scales[seg * 2 + 1] = 0.7f * am;  // threshold
    }
    __syncthreads();
  }
}

// ---------- ternarize: fp32 w -> bf16 q in {-1,0,+1} ----------
__global__ void k_ternarize(const float4* __restrict__ w, ushort4* __restrict__ q,
                            const float* __restrict__ scales, int sidx, int n4) {
  const float thr = scales[sidx * 2 + 1];
  const int stride = gridDim.x * blockDim.x;
  for (int i = blockIdx.x * blockDim.x + threadIdx.x; i < n4; i += stride) {
    float4 v = w[i];
    ushort4 o;
    o.x = v.x > thr ? 0x3F80u : (v.x < -thr ? 0xBF80u : 0u);
    o.y = v.y > thr ? 0x3F80u : (v.y < -thr ? 0xBF80u : 0u);
    o.z = v.z > thr ? 0x3F80u : (v.z < -thr ? 0xBF80u : 0u);
    o.w = v.w > thr ? 0x3F80u : (v.w < -thr ? 0xBF80u : 0u);
    q[i] = o;
  }
}

// ---------- x: fp32 -> bf16 ----------
__global__ void k_f32_to_bf16(const float4* __restrict__ x, ushort4* __restrict__ o,
                              int n4) {
  const int stride = gridDim.x * blockDim.x;
  for (int i = blockIdx.x * blockDim.x + threadIdx.x; i < n4; i += stride) {
    float4 v = x[i];
    ushort4 r;
    r.x = f2bf(v.x);
    r.y = f2bf(v.y);
    r.z = f2bf(v.z);
    r.w = f2bf(v.w);
    o[i] = r;
  }
}

// ================= 256x256 8-wave pipelined GEMM =================
// C = A * B^T. A[M][K], B[N][K] bf16; fp32 acc.
// LDS per buffer: A[256][64] @ +0, B[256][64] @ +16384 (shorts); dbuf = 128 KiB.
// Swizzle: LDS linear; global src col pre-permuted so that
// LDS[row][c] = G[row][c ^ 8*(row&7)] (elems); frag reads XOR the same.

#define ST1(Gst, base, r0, k0)                          \
  gload_lds16(Gst + (size_t)(r0) * K + (k0),            \
              (void*)(lptr + (base) + (r0) * 64))

#define ST_AQ0(pp, k0) do { ST1(Ast, (pp)*32768, w8, k0);        ST1(Ast, (pp)*32768, 128 + w8, k0); } while (0)
#define ST_AQ1(pp, k0) do { ST1(Ast, (pp)*32768, 64 + w8, k0);   ST1(Ast, (pp)*32768, 192 + w8, k0); } while (0)
#define ST_BQ0(pp, k0) do { ST1(Bst, (pp)*32768 + 16384, rb, k0);      ST1(Bst, (pp)*32768 + 16384, 128 + rb, k0); } while (0)
#define ST_BQ1(pp, k0) do { ST1(Bst, (pp)*32768 + 16384, 32 + rb, k0); ST1(Bst, (pp)*32768 + 16384, 160 + rb, k0); } while (0)

#define LDA(dst, p_, qr)                                                       \
  do {                                                                         \
    const unsigned short* ab =                                                 \
        lptr + (p_) * 32768 + (wr * 128 + (qr) * 64 + fr) * 64;                \
    _Pragma("unroll") for (int ri = 0; ri < 4; ++ri) {                         \
      dst[ri][0] = *(const short8*)(ab + ri * 1024 + csw0);                    \
      dst[ri][1] = *(const short8*)(ab + ri * 1024 + csw1);                    \
    }                                                                          \
  } while (0)

#define LDB(p_, qc)                                                            \
  do {                                                                         \
    const unsigned short* bb =                                                 \
        lptr + (p_) * 32768 + 16384 + (wc * 64 + (qc) * 32 + fr) * 64;         \
    _Pragma("unroll") for (int ci = 0; ci < 2; ++ci) {                         \
      bq[ci][0] = *(const short8*)(bb + ci * 1024 + csw0);                     \
      bq[ci][1] = *(const short8*)(bb + ci * 1024 + csw1);                     \
    }                                                                          \
  } while (0)

#define MFMA_PHASE(afv, qr, qc)                                                \
  do {                                                                         \
    __builtin_amdgcn_s_setprio(1);                                             \
    _Pragma("unroll") for (int kk = 0; kk < 2; ++kk)                           \
    _Pragma("unroll") for (int ri = 0; ri < 4; ++ri)                           \
    _Pragma("unroll") for (int ci = 0; ci < 2; ++ci)                           \
      acc[(qr) * 4 + ri][(qc) * 2 + ci] =                                      \
          __builtin_amdgcn_mfma_f32_16x16x32_bf16(                             \
              afv[ri][kk], bq[ci][kk], acc[(qr) * 4 + ri][(qc) * 2 + ci], 0,   \
              0, 0);                                                           \
    __builtin_amdgcn_s_setprio(0);                                             \
  } while (0)

#define BAR()                           \
  do {                                  \
    asm volatile("" ::: "memory");      \
    __builtin_amdgcn_s_barrier();       \
    asm volatile("" ::: "memory");      \
  } while (0)

#define WAIT_LGKM0() asm volatile("s_waitcnt lgkmcnt(0)" ::: "memory")

template <int EPI>
__global__ __launch_bounds__(512, 2) void k_gemm_bt(
    const unsigned short* __restrict__ A, const unsigned short* __restrict__ B,
    void* __restrict__ Cout, int M, int N, int K,
    const float* __restrict__ scales, int sidx, int nbx) {
  __shared__ __align__(16) unsigned short lds[2 * 2 * 256 * 64];  // 128 KiB
  unsigned short* lptr = lds;

  const int tid = threadIdx.x;
  const int lane = tid & 63;
  const int w = tid >> 6;   // wave 0..7
  const int wr = w >> 2;    // 0..1 -> 128 rows
  const int wc = w & 3;     // 0..3 -> 64 cols

  // T1: bijective XCD swizzle (gridDim.x % 8 == 0)
  const int nwg = gridDim.x;
  const int cpx = nwg >> 3;
  const int bid = blockIdx.x;
  const int swz = (bid & 7) * cpx + (bid >> 3);
  const int bm = swz / nbx;
  const int bn = swz % nbx;
  const int rowA0 = bm * BM;
  const int rowB0 = bn * BN;

  // staging lane geometry: row within 8-row chunk + pre-swizzled source col
  const int srow = lane >> 3;
  const int scol = ((lane & 7) ^ srow) << 3;  // bf16 elems
  const unsigned short* Ast = A + (size_t)(rowA0 + srow) * K + scol;
  const unsigned short* Bst = B + (size_t)(rowB0 + srow) * K + scol;

  // frag-read lane geometry (read col XORed with 8*(row&7), row&7 == fr&7)
  const int fr = lane & 15;
  const int kgrp = lane >> 4;
  const int csw0 = (kgrp << 3) ^ ((fr & 7) << 3);
  const int csw1 = (32 + (kgrp << 3)) ^ ((fr & 7) << 3);

  const int w8 = w << 3;
  const int rb = ((w >> 2) << 6) + ((w & 3) << 3);

  f32x4 acc[8][4];
#pragma unroll
  for (int i = 0; i < 8; ++i)
#pragma unroll
    for (int j = 0; j < 4; ++j) acc[i][j] = (f32x4){0.f, 0.f, 0.f, 0.f};

  short8 af0[4][2], af1[4][2], bq[2][2];

  const int nk = K / BK;

  // prologue (FIFO): tile0 {Bq0,Aq1,Aq0,Bq1}, tile1 {Bq0,Aq1}
  ST_BQ0(0, 0);
  ST_AQ1(0, 0);
  ST_AQ0(0, 0);
  ST_BQ1(0, 0);
  if (nk > 1) {
    ST_BQ0(1, BK);
    ST_AQ1(1, BK);
    asm volatile("s_waitcnt vmcnt(4)" ::: "memory");  // tile0 fully staged
  } else {
    asm volatile("s_waitcnt vmcnt(0)" ::: "memory");
  }
  BAR();

  int p = 0;
  for (int T = 0; T < nk; ++T, p ^= 1) {
    const int pn = p ^ 1;
    const int k1 = (T + 1) * BK;
    const int k2 = (T + 2) * BK;

    // ---- P1 (qr=0,qc=0): read A0,B0 pre-barrier; stage AQ0(T+1) ----
    LDA(af0, p, 0);
    LDB(p, 0);
    if (T + 1 < nk) ST_AQ0(pn, k1);
    asm volatile("s_waitcnt lgkmcnt(8)" ::: "memory");  // partial drain (12 issued)
    BAR();
    WAIT_LGKM0();
    MFMA_PHASE(af0, 0, 0);
    BAR();

    // ---- P2 (qr=1,qc=0): read A1; reuse bq; stage BQ1(T+1) ----
    LDA(af1, p, 1);
    if (T + 1 < nk) ST_BQ1(pn, k1);
    BAR();
    WAIT_LGKM0();
    MFMA_PHASE(af1, 1, 0);
    BAR();

    // ---- P3 (qr=1,qc=1): read B1; reuse af1; stage BQ0(T+2) ----
    LDB(p, 1);
    if (T + 2 < nk) ST_BQ0(p, k2);
    BAR();
    WAIT_LGKM0();
    MFMA_PHASE(af1, 1, 1);
    BAR();

    // ---- P4 (qr=0,qc=1): no reads (af0 held, bq reused); stage AQ1(T+2) ----
    if (T + 2 < nk) ST_AQ1(p, k2);
    BAR();
    MFMA_PHASE(af0, 0, 1);
    // tile-boundary gate: force tile T+1 buffer complete, keep T+2 in flight
    if (T + 1 < nk) {
      if (T + 2 < nk) {
        asm volatile("s_waitcnt vmcnt(4)" ::: "memory");
      } else {
        asm volatile("s_waitcnt vmcnt(0)" ::: "memory");
      }
    }
    BAR();
  }

  // epilogue: C/D layout col = lane&15, row = (lane>>4)*4 + q
  const float s = scales[sidx * 2];
  const int crow0 = rowA0 + wr * 128 + (lane >> 4) * 4;
  const int ccol0 = rowB0 + wc * 64 + (lane & 15);
  if (EPI == 0) {
    const float s2 = s * s;
    unsigned short* C = (unsigned short*)Cout;
#pragma unroll
    for (int ri = 0; ri < 8; ++ri)
#pragma unroll
      for (int ci = 0; ci < 4; ++ci)
#pragma unroll
        for (int q = 0; q < 4; ++q) {
          float v = acc[ri][ci][q];
          v = fmaxf(v, 0.0f);
          v = v * v * s2;
          C[(size_t)(crow0 + ri * 16 + q) * N + (ccol0 + ci * 16)] = f2bf(v);
        }
  } else {
    float* C = (float*)Cout;
#pragma unroll
    for (int ri = 0; ri < 8; ++ri)
#pragma unroll
      for (int ci = 0; ci < 4; ++ci)
#pragma unroll
        for (int q = 0; q < 4; ++q)
          C[(size_t)(crow0 + ri * 16 + q) * N + (ccol0 + ci * 16)] =
              acc[ri][ci][q] * s;
  }
}

extern "C" void kernel_launch(void* const* d_in, const int* in_sizes, int n_in,
                              void* d_out, int out_size, void* d_ws, size_t ws_size,
                              hipStream_t stream) {
  const int Mdim = 32768;  // B*S
  const int Ddim = 2048;
  const int Hdim = 5120;
  const int NW = Hdim * Ddim;  // elements per weight

  const float* x = (const float*)d_in[0];
  const float* w_fc = (const float*)d_in[1];
  const float* w_proj = (const float*)d_in[2];
  float* out = (float*)d_out;

  char* ws = (char*)d_ws;
  double* partial = (double*)ws;                          // 16 KB
  float* scales = (float*)(ws + 16384);                   // 4 floats
  unsigned short* wq_fc = (unsigned short*)(ws + 32768);  // 20 MB
  unsigned short* wq_proj = wq_fc + (size_t)NW;           // 20 MB
  unsigned short* xbf = wq_proj + (size_t)NW;             // 128 MB
  unsigned short* hbf = xbf + (size_t)Mdim * Ddim;        // 320 MB

  // 1) abs-mean reductions (deterministic, fp64)
  k_reduce_abs<<<1024, 256, 0, stream>>>((const float4*)w_fc, NW / 4, partial);
  k_reduce_abs<<<1024, 256, 0, stream>>>((const float4*)w_proj, NW / 4,
                                         partial + 1024);
  k_finalize<<<1, 256, 0, stream>>>(partial, scales, 1.0 / (double)NW);

  // 2) ternarize weights -> bf16 q
  k_ternarize<<<2048, 256, 0, stream>>>((const float4*)w_fc, (ushort4*)wq_fc,
                                        scales, 0, NW / 4);
  k_ternarize<<<2048, 256, 0, stream>>>((const float4*)w_proj, (ushort4*)wq_proj,
                                        scales, 1, NW / 4);

  // 3) x -> bf16
  k_f32_to_bf16<<<2048, 256, 0, stream>>>((const float4*)x, (ushort4*)xbf,
                                          (Mdim * Ddim) / 4);

  // 4) h = relu(x @ Wfc^T * s)^2  [M x H] bf16
  k_gemm_bt<0><<<dim3((Hdim / BN) * (Mdim / BM)), 512, 0, stream>>>(
      xbf, wq_fc, hbf, Mdim, Hdim, Ddim, scales, 0, Hdim / BN);

  // 5) out = h @ Wproj^T * s  [M x D] fp32
  k_gemm_bt<1><<<dim3((Ddim / BN) * (Mdim / BM)), 512, 0, stream>>>(
      hbf, wq_proj, out, Mdim, Ddim, Hdim, scales, 1, Ddim / BN);
}